// Round 19
// baseline (209.139 us; speedup 1.0000x reference)
//
#include <hip/hip_runtime.h>

#define BB 4
#define LL 2048
#define EE 1024
#define HH 8
#define DD 128
#define OO 1024
#define MM (BB*LL)   // 8192
#define ND (HH*DD)   // 1024

#define QBLK 128
#define KVBLK 64
#define NT (LL / KVBLK)

// log2(e)/sqrt(128): folded into qx at proj-q epilogue
#define C2 0.12751920678739807f

typedef __bf16 bf16;
typedef unsigned short u16;
typedef __bf16 bf16x8 __attribute__((ext_vector_type(8)));
typedef __bf16 bf16x4 __attribute__((ext_vector_type(4)));
typedef float  f32x4  __attribute__((ext_vector_type(4)));

// async global->LDS, 16B per lane; LDS dest = wave-uniform base + lane*16
__device__ __forceinline__ void gl16(const bf16* g, bf16* l) {
#if __has_builtin(__builtin_amdgcn_global_load_lds)
    __builtin_amdgcn_global_load_lds((const __attribute__((address_space(1))) char*)g,
                                     (__attribute__((address_space(3))) char*)l, 16, 0, 0);
#else
    *(bf16x8*)l = *(const bf16x8*)g;
#endif
}

// raw v_exp_f32 (args provably in (0,16.4]: no fixup needed)
__device__ __forceinline__ float fexp2(float x) {
#if __has_builtin(__builtin_amdgcn_exp2f)
    return __builtin_amdgcn_exp2f(x);
#else
    return exp2f(x);
#endif
}

__device__ __forceinline__ bf16x8 cvt8p(float4 f0, float4 f1) {
    bf16x8 v;
    v[0] = (bf16)f0.x; v[1] = (bf16)f0.y; v[2] = (bf16)f0.z; v[3] = (bf16)f0.w;
    v[4] = (bf16)f1.x; v[5] = (bf16)f1.y; v[6] = (bf16)f1.z; v[7] = (bf16)f1.w;
    return v;
}

// ---------------------------------------------------------------------------
// dtype detector (1 wave, parallel)
// ---------------------------------------------------------------------------
__global__ void detect_kernel(const u16* __restrict__ data, int* __restrict__ mode) {
    const int l = threadIdx.x;   // 64 threads
    int cnt = 0;
#pragma unroll
    for (int i = 0; i < 8; i++) {
        int e = (data[l * 8 + i] >> 7) & 0xFF;
        cnt += (e >= 117 && e <= 132) ? 1 : 0;
    }
    cnt += __shfl_xor(cnt, 1);
    cnt += __shfl_xor(cnt, 2);
    cnt += __shfl_xor(cnt, 4);
    cnt += __shfl_xor(cnt, 8);
    cnt += __shfl_xor(cnt, 16);
    cnt += __shfl_xor(cnt, 32);
    if (l == 0) *mode = (cnt > 400) ? 1 : 0;
}

__global__ __launch_bounds__(256) void fill_kernel(float* __restrict__ out, float v, int n) {
    int i = blockIdx.x * 256 + threadIdx.x;
    if (i < n) out[i] = v;
}

// ---------------------------------------------------------------------------
// w [H, E, D] (f32 or bf16)  ->  wT [H, D, E] bf16   (both weights, y=which)
// ---------------------------------------------------------------------------
__global__ __launch_bounds__(256) void wtrans_kernel(const void* __restrict__ in0,
                                                     const void* __restrict__ in1,
                                                     bf16* __restrict__ outT0,
                                                     bf16* __restrict__ outT1,
                                                     const int* __restrict__ mode) {
    const void* in = blockIdx.y ? in1 : in0;
    bf16* outT = blockIdx.y ? outT1 : outT0;
    int idx = blockIdx.x * 256 + threadIdx.x;   // over H*E*D/4
    int i4 = idx * 4;
    int h = i4 >> 17;            // E*D = 131072
    int rem = i4 & 131071;
    int e = rem >> 7;            // D = 128
    int d = rem & 127;
    size_t ob = ((size_t)h * DD + d) * EE + e;
    if (*mode) {
        bf16x4 v = *(const bf16x4*)((const bf16*)in + i4);
        outT[ob]          = v[0];
        outT[ob + EE]     = v[1];
        outT[ob + 2 * EE] = v[2];
        outT[ob + 3 * EE] = v[3];
    } else {
        float4 v = *(const float4*)((const float*)in + i4);
        outT[ob]          = (bf16)v.x;
        outT[ob + EE]     = (bf16)v.y;
        outT[ob + 2 * EE] = (bf16)v.z;
        outT[ob + 3 * EE] = (bf16)v.w;
    }
}

// ---------------------------------------------------------------------------
// Unified 8192x1024x1024 GEMM, C = A @ BT^T.  128x128 tile, BK=64, 4 waves.
// Single-LDS-buffer (r17 schedule) with DISTANCE-2 f32 register prefetch:
// even tiles use rSa, odd rSb; each buffer's loads are issued after tile t's
// second barrier and consumed at tile t+2's staging (~2 compute phases of
// cover vs ~900cy HBM latency).  bf16 operand via global_load_lds with
// inverse-swizzled source.
// epi==3: merged projections, 1024 blocks; half 0: sigmoid -> outBF0 + outT
//         (kxT layout), half 1: sigmoid*C2 -> outBF1 (qx pre-scaled).
// epi==2: out-proj, 512 blocks: +bias -> outF (f32).
// ---------------------------------------------------------------------------
__global__ __launch_bounds__(256) void gemm_kernel(const void* __restrict__ A0,
                                                   const void* __restrict__ A1,
                                                   const void* __restrict__ BT0,
                                                   const void* __restrict__ BT1,
                                                   bf16* __restrict__ outBF0,
                                                   bf16* __restrict__ outBF1,
                                                   bf16* __restrict__ outT,
                                                   float* __restrict__ outF,
                                                   const void* __restrict__ PB,
                                                   const int* __restrict__ mode,
                                                   const int epi) {
    __shared__ __align__(16) bf16 As[128 * 64];
    __shared__ __align__(16) bf16 Bs[128 * 64];
    const int md = *mode;
    const int t = threadIdx.x;
    const int w = t >> 6, l = t & 63;
    const int lr = l & 15, lg = l >> 4;
    const int wr = w >> 1, wc = w & 1;
    // XCD-grouped remap (bijective per 512-block half)
    const int o = blockIdx.x + (blockIdx.y << 3);
    const int half = (epi == 3) ? (o >> 9) : 0;
    const int oo = o & 511;
    const int mt = (oo & 7) * 8 + ((oo >> 3) & 7);
    const int ntile = oo >> 6;
    const int m0 = mt * 128, n0 = ntile * 128;
    const void* A = half ? A1 : A0;
    const void* BT = half ? BT1 : BT0;

    // f32-side (reg-prefetched, distance 2) vs bf16-side (global_load_lds)
    const int useF = (md == 0);
    const int fIsA = (epi == 3);
    const float* fS = (const float*)(fIsA ? A : BT);
    bf16* fDst = fIsA ? As : Bs;
    const int f0 = fIsA ? m0 : n0;
    const bf16* gS = (const bf16*)(fIsA ? BT : A);
    bf16* gDst = fIsA ? Bs : As;
    const int g0 = fIsA ? n0 : m0;

    f32x4 acc[4][4];
    const f32x4 zero = {0.f, 0.f, 0.f, 0.f};
#pragma unroll
    for (int i = 0; i < 4; i++)
#pragma unroll
        for (int j = 0; j < 4; j++) acc[i][j] = zero;

    float4 rSa[4][2], rSb[4][2];
    if (useF) {
#pragma unroll
        for (int p = 0; p < 4; p++) {
            const int id = p * 256 + t;
            const int row = id >> 3, cc = id & 7;
            const float* src = fS + (size_t)(f0 + row) * 1024 + cc * 8;
            rSa[p][0] = *(const float4*)src;
            rSa[p][1] = *(const float4*)(src + 4);
            rSb[p][0] = *(const float4*)(src + 64);
            rSb[p][1] = *(const float4*)(src + 68);
        }
    }

#define GTILE(KT, RS)                                                          \
    {                                                                          \
        const int k0 = (KT) * 64;                                              \
        __syncthreads();                                                       \
        if (useF) {                                                            \
            _Pragma("unroll") for (int p = 0; p < 4; p++) {                    \
                const int id = p * 256 + t;                                    \
                const int row = id >> 3, cc = id & 7;                          \
                *(bf16x8*)(fDst + row * 64 + ((cc ^ (row & 7)) << 3)) =        \
                    cvt8p(RS[p][0], RS[p][1]);                                 \
            }                                                                  \
            _Pragma("unroll") for (int p = 0; p < 4; p++) {                    \
                const int id = p * 256 + t;                                    \
                const int row = id >> 3;                                       \
                const int c = (id & 7) ^ (row & 7);                            \
                gl16(gS + (size_t)(g0 + row) * 1024 + k0 + c * 8,              \
                     gDst + (p * 256 + w * 64) * 8);                           \
            }                                                                  \
        } else {                                                               \
            _Pragma("unroll") for (int p = 0; p < 4; p++) {                    \
                const int id = p * 256 + t;                                    \
                const int row = id >> 3;                                       \
                const int c = (id & 7) ^ (row & 7);                            \
                gl16((const bf16*)A + (size_t)(m0 + row) * 1024 + k0 + c * 8,  \
                     As + (p * 256 + w * 64) * 8);                             \
                gl16((const bf16*)BT + (size_t)(n0 + row) * 1024 + k0 + c * 8, \
                     Bs + (p * 256 + w * 64) * 8);                             \
            }                                                                  \
        }                                                                      \
        __syncthreads();                                                       \
        if (useF && (KT) + 2 < 16) {                                           \
            const int k0p = k0 + 128;                                          \
            _Pragma("unroll") for (int p = 0; p < 4; p++) {                    \
                const int id = p * 256 + t;                                    \
                const int row = id >> 3, cc = id & 7;                          \
                const float* src = fS + (size_t)(f0 + row) * 1024 + k0p + cc * 8; \
                RS[p][0] = *(const float4*)src;                                \
                RS[p][1] = *(const float4*)(src + 4);                          \
            }                                                                  \
        }                                                                      \
        bf16x8 af[4][2], bg[4][2];                                             \
        _Pragma("unroll") for (int i = 0; i < 4; i++) {                        \
            const int ar = wr * 64 + i * 16 + lr;                              \
            _Pragma("unroll") for (int ks = 0; ks < 2; ks++)                   \
                af[i][ks] = *(const bf16x8*)(As + ar * 64 + (((ks * 4 + lg) ^ (ar & 7)) << 3)); \
        }                                                                      \
        _Pragma("unroll") for (int j = 0; j < 4; j++) {                        \
            const int br = wc * 64 + j * 16 + lr;                              \
            _Pragma("unroll") for (int ks = 0; ks < 2; ks++)                   \
                bg[j][ks] = *(const bf16x8*)(Bs + br * 64 + (((ks * 4 + lg) ^ (br & 7)) << 3)); \
        }                                                                      \
        _Pragma("unroll") for (int i = 0; i < 4; i++)                          \
            _Pragma("unroll") for (int j = 0; j < 4; j++) {                    \
                acc[i][j] = __builtin_amdgcn_mfma_f32_16x16x32_bf16(af[i][0], bg[j][0], acc[i][j], 0, 0, 0); \
                acc[i][j] = __builtin_amdgcn_mfma_f32_16x16x32_bf16(af[i][1], bg[j][1], acc[i][j], 0, 0, 0); \
            }                                                                  \
    }

    for (int kt = 0; kt < 16; kt += 2) {
        GTILE(kt, rSa)
        GTILE(kt + 1, rSb)
    }
#undef GTILE

    if (epi == 3) {
        bf16* outBF = half ? outBF1 : outBF0;
        const float mulf = half ? C2 : 1.0f;
        const int b_idx = m0 >> 11;
        const int h = n0 >> 7;
#pragma unroll
        for (int i = 0; i < 4; i++) {
#pragma unroll
            for (int j = 0; j < 4; j++) {
                const int gr = m0 + wr * 64 + i * 16 + lg * 4;
                const int gc = n0 + wc * 64 + j * 16 + lr;
                float s0 = mulf / (1.0f + __expf(-acc[i][j][0]));
                float s1 = mulf / (1.0f + __expf(-acc[i][j][1]));
                float s2 = mulf / (1.0f + __expf(-acc[i][j][2]));
                float s3 = mulf / (1.0f + __expf(-acc[i][j][3]));
                outBF[(size_t)gr * ND + gc]           = (bf16)s0;
                outBF[(size_t)(gr + 1) * ND + gc]     = (bf16)s1;
                outBF[(size_t)(gr + 2) * ND + gc]     = (bf16)s2;
                outBF[(size_t)(gr + 3) * ND + gc]     = (bf16)s3;
                if (!half) {
                    bf16x4 pk;
                    pk[0] = (bf16)s0; pk[1] = (bf16)s1; pk[2] = (bf16)s2; pk[3] = (bf16)s3;
                    const int d = gc & 127;
                    const int lrow = gr & 2047;
                    *(bf16x4*)(outT + (((size_t)(h * BB + b_idx)) * DD + d) * LL + lrow) = pk;
                }
            }
        }
    } else {
#pragma unroll
        for (int j = 0; j < 4; j++) {
            const int gc = n0 + wc * 64 + j * 16 + lr;
            const float bias = md ? (float)((const bf16*)PB)[gc] : ((const float*)PB)[gc];
#pragma unroll
            for (int i = 0; i < 4; i++) {
                const int gr = m0 + wr * 64 + i * 16 + lg * 4;
#pragma unroll
                for (int reg = 0; reg < 4; reg++)
                    outF[(size_t)(gr + reg) * OO + gc] = acc[i][j][reg] + bias;
            }
        }
    }
}

// ---------------------------------------------------------------------------
// attention (round-17, unchanged): async gl_lds staging with pre-swizzled
// global source + linear LDS dest; K/V double-buffered, 1 barrier/tile;
// swapped QK^T = mfma(K,Q); PV = mfma(V^T,P) -> O^T; no-max softmax with
// raw v_exp_f32; kv-half-split body.
// ---------------------------------------------------------------------------
__global__ __launch_bounds__(512, 4) void attn_kernel(const bf16* __restrict__ QX,
                                                      const bf16* __restrict__ KX,
                                                      const bf16* __restrict__ KXT,
                                                      bf16* __restrict__ AO) {
    __shared__ __align__(16) bf16 Kl[2][KVBLK * 128];   // 32 KiB
    __shared__ __align__(16) bf16 Vt[2][128 * KVBLK];   // 32 KiB
    __shared__ __align__(16) bf16 Pl[8][16 * 64];       // 16 KiB
    const int t = threadIdx.x;
    const int w = t >> 6, l = t & 63;
    const int lr = l & 15, lg = l >> 4;
    // XCD-chunked remap: dispatched bid -> orig linear id (bh-major)
    const int bid = blockIdx.x;
    const int orig = (bid & 7) * 64 + (bid >> 3);
    const int bh = orig >> 4;
    const int h = bh & 7, b = bh >> 3;
    const int q0 = (orig & 15) * QBLK;
    const bf16* qxh = QX + (size_t)(b * LL) * ND + h * DD;
    const bf16* kxh = KX + (size_t)(b * LL) * ND + h * DD;
    const bf16* kxt = KXT + ((size_t)(h * BB + b)) * DD * LL;

    // staging: 2 K-chunks + 2 V-chunks per thread, LINEAR LDS dest id*16B,
    // global source chunk pre-swizzled (src = destchunk ^ (row & mask))
    const int kid1 = 512 + t;
    const int krow0 = t >> 4,    kcd0 = t & 15;
    const int krow1 = kid1 >> 4, kcd1 = kid1 & 15;
    const int vrow0 = t >> 3,    vcd0 = t & 7;
    const int vrow1 = kid1 >> 3, vcd1 = kid1 & 7;
    const bf16* kps0 = kxh + (size_t)krow0 * ND + (kcd0 ^ (krow0 & 15)) * 8;
    const bf16* kps1 = kxh + (size_t)krow1 * ND + (kcd1 ^ (krow1 & 15)) * 8;
    const bf16* vps0 = kxt + (size_t)vrow0 * LL + (vcd0 ^ (vrow0 & 7)) * 8;
    const bf16* vps1 = kxt + (size_t)vrow1 * LL + (vcd1 ^ (vrow1 & 7)) * 8;

    // Q fragments (q row = lane&15), register resident; QX pre-scaled by C2
    bf16x8 qf[4];
    const int qrow = q0 + w * 16 + lr;
#pragma unroll
    for (int s = 0; s < 4; s++)
        qf[s] = *(const bf16x8*)(qxh + (size_t)qrow * ND + s * 32 + lg * 8);

    // prologue: async-stage tile 0 -> buf0; barrier drains vmcnt
    gl16(kps0, Kl[0] + t * 8);
    gl16(kps1, Kl[0] + kid1 * 8);
    gl16(vps0, Vt[0] + t * 8);
    gl16(vps1, Vt[0] + kid1 * 8);
    __syncthreads();

    f32x4 oacc[8];   // O^T: oacc[n][reg] = O[d = n*16+lg*4+reg][q = lr]
    const f32x4 zero = {0.f, 0.f, 0.f, 0.f};
#pragma unroll
    for (int n = 0; n < 8; n++) oacc[n] = zero;
    float psum = 0.f;   // per-lane partial row sum for q = lr

    for (int kt = 0; kt < NT; ++kt) {
        const int cur = kt & 1;
        if (kt + 1 < NT) {
            const size_t ko = (size_t)(kt + 1) * KVBLK * ND;
            const int vo = (kt + 1) * KVBLK;
            gl16(kps0 + ko, Kl[cur ^ 1] + t * 8);
            gl16(kps1 + ko, Kl[cur ^ 1] + kid1 * 8);
            gl16(vps0 + vo, Vt[cur ^ 1] + t * 8);
            gl16(vps1 + vo, Vt[cur ^ 1] + kid1 * 8);
        }
        const bf16* KlC = Kl[cur];
        const bf16* VtC = Vt[cur];

        // ---- kv half A (n = 0,1; kv 0..31) ----
        f32x4 sa[4];
        __builtin_amdgcn_s_setprio(1);
#pragma unroll
        for (int n = 0; n < 2; n++) {
            sa[n] = zero;
#pragma unroll
            for (int ks = 0; ks < 4; ks++) {
                int arow = n * 16 + lr;   // kv row
                bf16x8 kb = *(const bf16x8*)(KlC + arow * 128 + ((((ks * 4 + lg) ^ (arow & 15))) << 3));
                sa[n] = __builtin_amdgcn_mfma_f32_16x16x32_bf16(kb, qf[ks], sa[n], 0, 0, 0);
            }
        }
        __builtin_amdgcn_s_setprio(0);
#pragma unroll
        for (int n = 0; n < 2; n++) {
            bf16x4 pk;
#pragma unroll
            for (int j = 0; j < 4; j++) {
                float p = fexp2(sa[n][j]);
                psum += p;
                pk[j] = (bf16)p;
            }
            const int chunk = (2 * n + (lg >> 1)) ^ (lr & 7);
            *(bf16x4*)(Pl[w] + lr * 64 + chunk * 8 + (lg & 1) * 4) = pk;
        }
        // ---- kv half B (n = 2,3; kv 32..63) — its MFMAs overlap half-A VALU ----
        __builtin_amdgcn_s_setprio(1);
#pragma unroll
        for (int n = 2; n < 4; n++) {
            sa[n] = zero;
#pragma unroll
            for (int ks = 0; ks < 4; ks++) {
                int arow = n * 16 + lr;
                bf16x8 kb = *(const bf16x8*)(KlC + arow * 128 + ((((ks * 4 + lg) ^ (arow & 15))) << 3));
                sa[n] = __builtin_amdgcn_mfma_f32_16x16x32_bf16(kb, qf[ks], sa[n], 0, 0, 0);
            }
        }
        __builtin_amdgcn_s_setprio(0);
#pragma unroll
        for (int n = 2; n < 4; n++) {
            bf16x4 pk;
#pragma unroll
            for (int j = 0; j < 4; j++) {
                float p = fexp2(sa[n][j]);
                psum += p;
                pk[j] = (bf16)p;
            }
            const int chunk = (2 * n + (lg >> 1)) ^ (lr & 7);
            *(bf16x4*)(Pl[w] + lr * 64 + chunk * 8 + (lg & 1) * 4) = pk;
        }
        // wave-local ordering: P stores above vs vector-loads below
        asm volatile("s_waitcnt lgkmcnt(0)" ::: "memory");
        __builtin_amdgcn_sched_barrier(0);
        // PV: O^T += V^T P  (A = V^T rows d, B = P rows q)
        bf16x8 pb0 = *(const bf16x8*)(Pl[w] + lr * 64 + (((lg ^ (lr & 7))) << 3));
        bf16x8 pb1 = *(const bf16x8*)(Pl[w] + lr * 64 + ((((4 + lg) ^ (lr & 7))) << 3));
        __builtin_amdgcn_s_setprio(1);
#pragma unroll
        for (int n = 0; n < 8; n++) {
            int vrow = n * 16 + lr;
            bf16x8 vb0 = *(const bf16x8*)(VtC + vrow * 64 + (((lg ^ (vrow & 7))) << 3));
            oacc[n] = __builtin_amdgcn_mfma_f32_16x16x32_bf16(vb0, pb0, oacc[n], 0, 0, 0);
            bf16x8 vb1 = *(const bf16x8*)(VtC + vrow * 64 + ((((4 + lg) ^ (vrow & 7))) << 3));
            oacc[n] = __builtin_amdgcn_mfma_f32_16x16x32_bf16(vb1, pb1, oacc[n], 0, 0, 0);
        }
        __builtin_amdgcn_s_setprio(0);
        __syncthreads();
    }
    // epilogue: reduce psum across the 4 lane-groups holding q = lr
    float tot = psum;
    tot += __shfl_xor(tot, 16);
    tot += __shfl_xor(tot, 32);
    const float linv = 1.0f / tot;
    const int arow = b * LL + q0 + w * 16 + lr;   // one output row per lane
    bf16* aoRow = AO + (size_t)arow * ND + h * DD;
#pragma unroll
    for (int n = 0; n < 8; n++) {
        bf16x4 o;
#pragma unroll
        for (int reg = 0; reg < 4; reg++) o[reg] = (bf16)(oacc[n][reg] * linv);
        *(bf16x4*)(aoRow + n * 16 + lg * 4) = o;
    }
}

extern "C" void kernel_launch(void* const* d_in, const int* in_sizes, int n_in,
                              void* d_out, int out_size, void* d_ws, size_t ws_size,
                              hipStream_t stream) {
    (void)in_sizes; (void)n_in;
    float* out = (float*)d_out;

    const size_t NEED = ((size_t)(2 + 2 + 16 + 16 + 16 + 16) << 20) + 256;
    if (ws_size < NEED) {
        hipLaunchKernelGGL(fill_kernel, dim3((out_size + 255) / 256), dim3(256), 0, stream,
                           out, (float)(ws_size >> 20), out_size);
        return;
    }

    int* mode = (int*)d_ws;
    bf16* base = (bf16*)((char*)d_ws + 256);
    bf16* wkT = base;                              // [H, D, E]   2 MiB
    bf16* wqT = wkT + (size_t)HH * DD * EE;        // [H, D, E]   2 MiB
    bf16* kx  = wqT + (size_t)HH * DD * EE;        // [M, ND]    16 MiB
    bf16* qx  = kx  + (size_t)MM * ND;             // [M, ND]    16 MiB
    bf16* kxT = qx  + (size_t)MM * ND;             // [H, B, D, L] 16 MiB
    bf16* ao  = kxT + (size_t)HH * MM * DD;        // [M, ND]    16 MiB

    hipLaunchKernelGGL(detect_kernel, dim3(1), dim3(64), 0, stream, (const u16*)d_in[0], mode);
    hipLaunchKernelGGL(wtrans_kernel, dim3(HH * EE * DD / 4 / 256, 2), dim3(256), 0, stream,
                       d_in[2], d_in[3], wkT, wqT, mode);
    // merged proj-k (sigmoid + kxT) and proj-q (sigmoid*C2): 1024 blocks
    hipLaunchKernelGGL(gemm_kernel, dim3(8, 128), dim3(256), 0, stream,
                       d_in[0], d_in[1], wkT, wqT, kx, qx, kxT,
                       (float*)nullptr, (const void*)nullptr, mode, 3);
    // attention
    hipLaunchKernelGGL(attn_kernel, dim3(512), dim3(512), 0, stream, qx, kx, kxT, ao);
    // out-proj (+bias, f32 out); B = proj_w (f32 reg-staged or bf16 gload)
    hipLaunchKernelGGL(gemm_kernel, dim3(8, 64), dim3(256), 0, stream,
                       ao, (const void*)nullptr, d_in[4], (const void*)nullptr,
                       (bf16*)nullptr, (bf16*)nullptr, (bf16*)nullptr, out, d_in[5], mode, 2);
}

// Round 20
// 170.263 us; speedup vs baseline: 1.2283x; 1.2283x over previous
//
#include <hip/hip_runtime.h>

#define BB 4
#define LL 2048
#define EE 1024
#define HH 8
#define DD 128
#define OO 1024
#define MM (BB*LL)   // 8192
#define ND (HH*DD)   // 1024

#define QBLK 128
#define KVBLK 64
#define NT (LL / KVBLK)

// log2(e)/sqrt(128): folded into qx at proj-q epilogue
#define C2 0.12751920678739807f

typedef __bf16 bf16;
typedef unsigned short u16;
typedef __bf16 bf16x8 __attribute__((ext_vector_type(8)));
typedef __bf16 bf16x4 __attribute__((ext_vector_type(4)));
typedef float  f32x4  __attribute__((ext_vector_type(4)));

// async global->LDS, 16B per lane; LDS dest = wave-uniform base + lane*16
__device__ __forceinline__ void gl16(const bf16* g, bf16* l) {
#if __has_builtin(__builtin_amdgcn_global_load_lds)
    __builtin_amdgcn_global_load_lds((const __attribute__((address_space(1))) char*)g,
                                     (__attribute__((address_space(3))) char*)l, 16, 0, 0);
#else
    *(bf16x8*)l = *(const bf16x8*)g;
#endif
}

// raw v_exp_f32 (args provably in (0,16.4]: no fixup needed)
__device__ __forceinline__ float fexp2(float x) {
#if __has_builtin(__builtin_amdgcn_exp2f)
    return __builtin_amdgcn_exp2f(x);
#else
    return exp2f(x);
#endif
}

__device__ __forceinline__ bf16x8 cvt8p(float4 f0, float4 f1) {
    bf16x8 v;
    v[0] = (bf16)f0.x; v[1] = (bf16)f0.y; v[2] = (bf16)f0.z; v[3] = (bf16)f0.w;
    v[4] = (bf16)f1.x; v[5] = (bf16)f1.y; v[6] = (bf16)f1.z; v[7] = (bf16)f1.w;
    return v;
}

// ---------------------------------------------------------------------------
// dtype detector (1 wave, parallel)
// ---------------------------------------------------------------------------
__global__ void detect_kernel(const u16* __restrict__ data, int* __restrict__ mode) {
    const int l = threadIdx.x;   // 64 threads
    int cnt = 0;
#pragma unroll
    for (int i = 0; i < 8; i++) {
        int e = (data[l * 8 + i] >> 7) & 0xFF;
        cnt += (e >= 117 && e <= 132) ? 1 : 0;
    }
    cnt += __shfl_xor(cnt, 1);
    cnt += __shfl_xor(cnt, 2);
    cnt += __shfl_xor(cnt, 4);
    cnt += __shfl_xor(cnt, 8);
    cnt += __shfl_xor(cnt, 16);
    cnt += __shfl_xor(cnt, 32);
    if (l == 0) *mode = (cnt > 400) ? 1 : 0;
}

__global__ __launch_bounds__(256) void fill_kernel(float* __restrict__ out, float v, int n) {
    int i = blockIdx.x * 256 + threadIdx.x;
    if (i < n) out[i] = v;
}

// ---------------------------------------------------------------------------
// w [H, E, D] (f32 or bf16)  ->  wT [H, D, E] bf16   (both weights, y=which)
// ---------------------------------------------------------------------------
__global__ __launch_bounds__(256) void wtrans_kernel(const void* __restrict__ in0,
                                                     const void* __restrict__ in1,
                                                     bf16* __restrict__ outT0,
                                                     bf16* __restrict__ outT1,
                                                     const int* __restrict__ mode) {
    const void* in = blockIdx.y ? in1 : in0;
    bf16* outT = blockIdx.y ? outT1 : outT0;
    int idx = blockIdx.x * 256 + threadIdx.x;   // over H*E*D/4
    int i4 = idx * 4;
    int h = i4 >> 17;            // E*D = 131072
    int rem = i4 & 131071;
    int e = rem >> 7;            // D = 128
    int d = rem & 127;
    size_t ob = ((size_t)h * DD + d) * EE + e;
    if (*mode) {
        bf16x4 v = *(const bf16x4*)((const bf16*)in + i4);
        outT[ob]          = v[0];
        outT[ob + EE]     = v[1];
        outT[ob + 2 * EE] = v[2];
        outT[ob + 3 * EE] = v[3];
    } else {
        float4 v = *(const float4*)((const float*)in + i4);
        outT[ob]          = (bf16)v.x;
        outT[ob + EE]     = (bf16)v.y;
        outT[ob + 2 * EE] = (bf16)v.z;
        outT[ob + 3 * EE] = (bf16)v.w;
    }
}

// ---------------------------------------------------------------------------
// Unified 8192x1024x1024 GEMM, C = A @ BT^T.  128x128 tile, BK=64, 4 waves.
// The f32 operand (A for epi3, B for epi2 when mode==0) is register-
// prefetched one K-tile ahead (loads issued after barrier-2 so they fly
// under the MFMAs); the bf16 operand always uses global_load_lds with
// inverse-swizzled source.
// epi==3: merged projections, 1024 blocks; half 0: sigmoid -> outBF0 + outT
//         (kxT layout), half 1: sigmoid*C2 -> outBF1 (qx pre-scaled).
// epi==2: out-proj, 512 blocks: +bias -> outF (f32).
// ---------------------------------------------------------------------------
__global__ __launch_bounds__(256) void gemm_kernel(const void* __restrict__ A0,
                                                   const void* __restrict__ A1,
                                                   const void* __restrict__ BT0,
                                                   const void* __restrict__ BT1,
                                                   bf16* __restrict__ outBF0,
                                                   bf16* __restrict__ outBF1,
                                                   bf16* __restrict__ outT,
                                                   float* __restrict__ outF,
                                                   const void* __restrict__ PB,
                                                   const int* __restrict__ mode,
                                                   const int epi) {
    __shared__ __align__(16) bf16 As[128 * 64];
    __shared__ __align__(16) bf16 Bs[128 * 64];
    const int md = *mode;
    const int t = threadIdx.x;
    const int w = t >> 6, l = t & 63;
    const int lr = l & 15, lg = l >> 4;
    const int wr = w >> 1, wc = w & 1;
    // XCD-grouped remap (bijective per 512-block half)
    const int o = blockIdx.x + (blockIdx.y << 3);
    const int half = (epi == 3) ? (o >> 9) : 0;
    const int oo = o & 511;
    const int mt = (oo & 7) * 8 + ((oo >> 3) & 7);
    const int ntile = oo >> 6;
    const int m0 = mt * 128, n0 = ntile * 128;
    const void* A = half ? A1 : A0;
    const void* BT = half ? BT1 : BT0;

    // f32-side (register-prefetched) vs bf16-side (global_load_lds) selection
    const int useF = (md == 0);
    const float* fS = (const float*)((epi == 3) ? A : BT);   // f32 operand
    bf16* fDst = (epi == 3) ? As : Bs;
    const int f0 = (epi == 3) ? m0 : n0;
    const bf16* gS = (const bf16*)((epi == 3) ? BT : A);     // the other operand
    bf16* gDst = (epi == 3) ? Bs : As;
    const int g0 = (epi == 3) ? n0 : m0;

    f32x4 acc[4][4];
    const f32x4 zero = {0.f, 0.f, 0.f, 0.f};
#pragma unroll
    for (int i = 0; i < 4; i++)
#pragma unroll
        for (int j = 0; j < 4; j++) acc[i][j] = zero;

    float4 rS[4][2];
    if (useF) {
#pragma unroll
        for (int p = 0; p < 4; p++) {
            const int id = p * 256 + t;
            const int row = id >> 3, cc = id & 7;
            const float* src = fS + (size_t)(f0 + row) * 1024 + cc * 8;
            rS[p][0] = *(const float4*)src;
            rS[p][1] = *(const float4*)(src + 4);
        }
    }

    for (int kt = 0; kt < 16; ++kt) {
        const int k0 = kt * 64;
        __syncthreads();
        if (useF) {
#pragma unroll
            for (int p = 0; p < 4; p++) {
                const int id = p * 256 + t;
                const int row = id >> 3, cc = id & 7;
                *(bf16x8*)(fDst + row * 64 + ((cc ^ (row & 7)) << 3)) = cvt8p(rS[p][0], rS[p][1]);
            }
#pragma unroll
            for (int p = 0; p < 4; p++) {
                const int id = p * 256 + t;
                const int row = id >> 3;
                const int c = (id & 7) ^ (row & 7);
                gl16(gS + (size_t)(g0 + row) * 1024 + k0 + c * 8, gDst + (p * 256 + w * 64) * 8);
            }
        } else {
#pragma unroll
            for (int p = 0; p < 4; p++) {
                const int id = p * 256 + t;
                const int row = id >> 3;
                const int c = (id & 7) ^ (row & 7);
                gl16((const bf16*)A + (size_t)(m0 + row) * 1024 + k0 + c * 8,
                     As + (p * 256 + w * 64) * 8);
                gl16((const bf16*)BT + (size_t)(n0 + row) * 1024 + k0 + c * 8,
                     Bs + (p * 256 + w * 64) * 8);
            }
        }
        __syncthreads();
        // issue next-tile f32 loads AFTER the barrier: they fly under the MFMAs
        if (useF && kt + 1 < 16) {
            const int k0n = k0 + 64;
#pragma unroll
            for (int p = 0; p < 4; p++) {
                const int id = p * 256 + t;
                const int row = id >> 3, cc = id & 7;
                const float* src = fS + (size_t)(f0 + row) * 1024 + k0n + cc * 8;
                rS[p][0] = *(const float4*)src;
                rS[p][1] = *(const float4*)(src + 4);
            }
        }
        bf16x8 af[4][2], bg[4][2];
#pragma unroll
        for (int i = 0; i < 4; i++) {
            const int ar = wr * 64 + i * 16 + lr;
#pragma unroll
            for (int ks = 0; ks < 2; ks++)
                af[i][ks] = *(const bf16x8*)(As + ar * 64 + (((ks * 4 + lg) ^ (ar & 7)) << 3));
        }
#pragma unroll
        for (int j = 0; j < 4; j++) {
            const int br = wc * 64 + j * 16 + lr;
#pragma unroll
            for (int ks = 0; ks < 2; ks++)
                bg[j][ks] = *(const bf16x8*)(Bs + br * 64 + (((ks * 4 + lg) ^ (br & 7)) << 3));
        }
#pragma unroll
        for (int i = 0; i < 4; i++)
#pragma unroll
            for (int j = 0; j < 4; j++) {
                acc[i][j] = __builtin_amdgcn_mfma_f32_16x16x32_bf16(af[i][0], bg[j][0], acc[i][j], 0, 0, 0);
                acc[i][j] = __builtin_amdgcn_mfma_f32_16x16x32_bf16(af[i][1], bg[j][1], acc[i][j], 0, 0, 0);
            }
    }

    if (epi == 3) {
        bf16* outBF = half ? outBF1 : outBF0;
        const float mulf = half ? C2 : 1.0f;
        const int b_idx = m0 >> 11;
        const int h = n0 >> 7;
#pragma unroll
        for (int i = 0; i < 4; i++) {
#pragma unroll
            for (int j = 0; j < 4; j++) {
                const int gr = m0 + wr * 64 + i * 16 + lg * 4;
                const int gc = n0 + wc * 64 + j * 16 + lr;
                float s0 = mulf / (1.0f + __expf(-acc[i][j][0]));
                float s1 = mulf / (1.0f + __expf(-acc[i][j][1]));
                float s2 = mulf / (1.0f + __expf(-acc[i][j][2]));
                float s3 = mulf / (1.0f + __expf(-acc[i][j][3]));
                outBF[(size_t)gr * ND + gc]           = (bf16)s0;
                outBF[(size_t)(gr + 1) * ND + gc]     = (bf16)s1;
                outBF[(size_t)(gr + 2) * ND + gc]     = (bf16)s2;
                outBF[(size_t)(gr + 3) * ND + gc]     = (bf16)s3;
                if (!half) {
                    bf16x4 pk;
                    pk[0] = (bf16)s0; pk[1] = (bf16)s1; pk[2] = (bf16)s2; pk[3] = (bf16)s3;
                    const int d = gc & 127;
                    const int lrow = gr & 2047;
                    *(bf16x4*)(outT + (((size_t)(h * BB + b_idx)) * DD + d) * LL + lrow) = pk;
                }
            }
        }
    } else {
#pragma unroll
        for (int j = 0; j < 4; j++) {
            const int gc = n0 + wc * 64 + j * 16 + lr;
            const float bias = md ? (float)((const bf16*)PB)[gc] : ((const float*)PB)[gc];
#pragma unroll
            for (int i = 0; i < 4; i++) {
                const int gr = m0 + wr * 64 + i * 16 + lg * 4;
#pragma unroll
                for (int reg = 0; reg < 4; reg++)
                    outF[(size_t)(gr + reg) * OO + gc] = acc[i][j][reg] + bias;
            }
        }
    }
}

// ---------------------------------------------------------------------------
// attention (round-17 structure): async gl_lds staging with pre-swizzled
// global source + linear LDS dest; K/V double-buffered, 1 barrier/tile;
// swapped QK^T = mfma(K,Q); PV = mfma(V^T,P) -> O^T; no-max softmax with
// raw v_exp_f32; kv-half-split body.
// ---------------------------------------------------------------------------
__global__ __launch_bounds__(512, 4) void attn_kernel(const bf16* __restrict__ QX,
                                                      const bf16* __restrict__ KX,
                                                      const bf16* __restrict__ KXT,
                                                      bf16* __restrict__ AO) {
    __shared__ __align__(16) bf16 Kl[2][KVBLK * 128];   // 32 KiB
    __shared__ __align__(16) bf16 Vt[2][128 * KVBLK];   // 32 KiB
    __shared__ __align__(16) bf16 Pl[8][16 * 64];       // 16 KiB
    const int t = threadIdx.x;
    const int w = t >> 6, l = t & 63;
    const int lr = l & 15, lg = l >> 4;
    // XCD-chunked remap: dispatched bid -> orig linear id (bh-major)
    const int bid = blockIdx.x;
    const int orig = (bid & 7) * 64 + (bid >> 3);
    const int bh = orig >> 4;
    const int h = bh & 7, b = bh >> 3;
    const int q0 = (orig & 15) * QBLK;
    const bf16* qxh = QX + (size_t)(b * LL) * ND + h * DD;
    const bf16* kxh = KX + (size_t)(b * LL) * ND + h * DD;
    const bf16* kxt = KXT + ((size_t)(h * BB + b)) * DD * LL;

    // staging: 2 K-chunks + 2 V-chunks per thread, LINEAR LDS dest id*16B,
    // global source chunk pre-swizzled (src = destchunk ^ (row & mask))
    const int kid1 = 512 + t;
    const int krow0 = t >> 4,    kcd0 = t & 15;
    const int krow1 = kid1 >> 4, kcd1 = kid1 & 15;
    const int vrow0 = t >> 3,    vcd0 = t & 7;
    const int vrow1 = kid1 >> 3, vcd1 = kid1 & 7;
    const bf16* kps0 = kxh + (size_t)krow0 * ND + (kcd0 ^ (krow0 & 15)) * 8;
    const bf16* kps1 = kxh + (size_t)krow1 * ND + (kcd1 ^ (krow1 & 15)) * 8;
    const bf16* vps0 = kxt + (size_t)vrow0 * LL + (vcd0 ^ (vrow0 & 7)) * 8;
    const bf16* vps1 = kxt + (size_t)vrow1 * LL + (vcd1 ^ (vrow1 & 7)) * 8;

    // Q fragments (q row = lane&15), register resident; QX pre-scaled by C2
    bf16x8 qf[4];
    const int qrow = q0 + w * 16 + lr;
#pragma unroll
    for (int s = 0; s < 4; s++)
        qf[s] = *(const bf16x8*)(qxh + (size_t)qrow * ND + s * 32 + lg * 8);

    // prologue: async-stage tile 0 -> buf0; barrier drains vmcnt
    gl16(kps0, Kl[0] + t * 8);
    gl16(kps1, Kl[0] + kid1 * 8);
    gl16(vps0, Vt[0] + t * 8);
    gl16(vps1, Vt[0] + kid1 * 8);
    __syncthreads();

    f32x4 oacc[8];   // O^T: oacc[n][reg] = O[d = n*16+lg*4+reg][q = lr]
    const f32x4 zero = {0.f, 0.f, 0.f, 0.f};
#pragma unroll
    for (int n = 0; n < 8; n++) oacc[n] = zero;
    float psum = 0.f;   // per-lane partial row sum for q = lr

    for (int kt = 0; kt < NT; ++kt) {
        const int cur = kt & 1;
        if (kt + 1 < NT) {
            const size_t ko = (size_t)(kt + 1) * KVBLK * ND;
            const int vo = (kt + 1) * KVBLK;
            gl16(kps0 + ko, Kl[cur ^ 1] + t * 8);
            gl16(kps1 + ko, Kl[cur ^ 1] + kid1 * 8);
            gl16(vps0 + vo, Vt[cur ^ 1] + t * 8);
            gl16(vps1 + vo, Vt[cur ^ 1] + kid1 * 8);
        }
        const bf16* KlC = Kl[cur];
        const bf16* VtC = Vt[cur];

        // ---- kv half A (n = 0,1; kv 0..31) ----
        f32x4 sa[4];
        __builtin_amdgcn_s_setprio(1);
#pragma unroll
        for (int n = 0; n < 2; n++) {
            sa[n] = zero;
#pragma unroll
            for (int ks = 0; ks < 4; ks++) {
                int arow = n * 16 + lr;   // kv row
                bf16x8 kb = *(const bf16x8*)(KlC + arow * 128 + ((((ks * 4 + lg) ^ (arow & 15))) << 3));
                sa[n] = __builtin_amdgcn_mfma_f32_16x16x32_bf16(kb, qf[ks], sa[n], 0, 0, 0);
            }
        }
        __builtin_amdgcn_s_setprio(0);
#pragma unroll
        for (int n = 0; n < 2; n++) {
            bf16x4 pk;
#pragma unroll
            for (int j = 0; j < 4; j++) {
                float p = fexp2(sa[n][j]);
                psum += p;
                pk[j] = (bf16)p;
            }
            const int chunk = (2 * n + (lg >> 1)) ^ (lr & 7);
            *(bf16x4*)(Pl[w] + lr * 64 + chunk * 8 + (lg & 1) * 4) = pk;
        }
        // ---- kv half B (n = 2,3; kv 32..63) — its MFMAs overlap half-A VALU ----
        __builtin_amdgcn_s_setprio(1);
#pragma unroll
        for (int n = 2; n < 4; n++) {
            sa[n] = zero;
#pragma unroll
            for (int ks = 0; ks < 4; ks++) {
                int arow = n * 16 + lr;
                bf16x8 kb = *(const bf16x8*)(KlC + arow * 128 + ((((ks * 4 + lg) ^ (arow & 15))) << 3));
                sa[n] = __builtin_amdgcn_mfma_f32_16x16x32_bf16(kb, qf[ks], sa[n], 0, 0, 0);
            }
        }
        __builtin_amdgcn_s_setprio(0);
#pragma unroll
        for (int n = 2; n < 4; n++) {
            bf16x4 pk;
#pragma unroll
            for (int j = 0; j < 4; j++) {
                float p = fexp2(sa[n][j]);
                psum += p;
                pk[j] = (bf16)p;
            }
            const int chunk = (2 * n + (lg >> 1)) ^ (lr & 7);
            *(bf16x4*)(Pl[w] + lr * 64 + chunk * 8 + (lg & 1) * 4) = pk;
        }
        // wave-local ordering: P stores above vs vector-loads below
        asm volatile("s_waitcnt lgkmcnt(0)" ::: "memory");
        __builtin_amdgcn_sched_barrier(0);
        // PV: O^T += V^T P  (A = V^T rows d, B = P rows q)
        bf16x8 pb0 = *(const bf16x8*)(Pl[w] + lr * 64 + (((lg ^ (lr & 7))) << 3));
        bf16x8 pb1 = *(const bf16x8*)(Pl[w] + lr * 64 + ((((4 + lg) ^ (lr & 7))) << 3));
        __builtin_amdgcn_s_setprio(1);
#pragma unroll
        for (int n = 0; n < 8; n++) {
            int vrow = n * 16 + lr;
            bf16x8 vb0 = *(const bf16x8*)(VtC + vrow * 64 + (((lg ^ (vrow & 7))) << 3));
            oacc[n] = __builtin_amdgcn_mfma_f32_16x16x32_bf16(vb0, pb0, oacc[n], 0, 0, 0);
            bf16x8 vb1 = *(const bf16x8*)(VtC + vrow * 64 + ((((4 + lg) ^ (vrow & 7))) << 3));
            oacc[n] = __builtin_amdgcn_mfma_f32_16x16x32_bf16(vb1, pb1, oacc[n], 0, 0, 0);
        }
        __builtin_amdgcn_s_setprio(0);
        __syncthreads();
    }
    // epilogue: reduce psum across the 4 lane-groups holding q = lr
    float tot = psum;
    tot += __shfl_xor(tot, 16);
    tot += __shfl_xor(tot, 32);
    const float linv = 1.0f / tot;
    const int arow = b * LL + q0 + w * 16 + lr;   // one output row per lane
    bf16* aoRow = AO + (size_t)arow * ND + h * DD;
#pragma unroll
    for (int n = 0; n < 8; n++) {
        bf16x4 o;
#pragma unroll
        for (int reg = 0; reg < 4; reg++) o[reg] = (bf16)(oacc[n][reg] * linv);
        *(bf16x4*)(aoRow + n * 16 + lg * 4) = o;
    }
}

extern "C" void kernel_launch(void* const* d_in, const int* in_sizes, int n_in,
                              void* d_out, int out_size, void* d_ws, size_t ws_size,
                              hipStream_t stream) {
    (void)in_sizes; (void)n_in;
    float* out = (float*)d_out;

    const size_t NEED = ((size_t)(2 + 2 + 16 + 16 + 16 + 16) << 20) + 256;
    if (ws_size < NEED) {
        hipLaunchKernelGGL(fill_kernel, dim3((out_size + 255) / 256), dim3(256), 0, stream,
                           out, (float)(ws_size >> 20), out_size);
        return;
    }

    int* mode = (int*)d_ws;
    bf16* base = (bf16*)((char*)d_ws + 256);
    bf16* wkT = base;                              // [H, D, E]   2 MiB
    bf16* wqT = wkT + (size_t)HH * DD * EE;        // [H, D, E]   2 MiB
    bf16* kx  = wqT + (size_t)HH * DD * EE;        // [M, ND]    16 MiB
    bf16* qx  = kx  + (size_t)MM * ND;             // [M, ND]    16 MiB
    bf16* kxT = qx  + (size_t)MM * ND;             // [H, B, D, L] 16 MiB
    bf16* ao  = kxT + (size_t)HH * MM * DD;        // [M, ND]    16 MiB

    hipLaunchKernelGGL(detect_kernel, dim3(1), dim3(64), 0, stream, (const u16*)d_in[0], mode);
    hipLaunchKernelGGL(wtrans_kernel, dim3(HH * EE * DD / 4 / 256, 2), dim3(256), 0, stream,
                       d_in[2], d_in[3], wkT, wqT, mode);
    // merged proj-k (sigmoid + kxT) and proj-q (sigmoid*C2): 1024 blocks
    hipLaunchKernelGGL(gemm_kernel, dim3(8, 128), dim3(256), 0, stream,
                       d_in[0], d_in[1], wkT, wqT, kx, qx, kxT,
                       (float*)nullptr, (const void*)nullptr, mode, 3);
    // attention
    hipLaunchKernelGGL(attn_kernel, dim3(512), dim3(512), 0, stream, qx, kx, kxT, ao);
    // out-proj (+bias, f32 out); B = proj_w (f32 reg-staged or bf16 gload)
    hipLaunchKernelGGL(gemm_kernel, dim3(8, 64), dim3(256), 0, stream,
                       ao, (const void*)nullptr, d_in[4], (const void*)nullptr,
                       (bf16*)nullptr, (bf16*)nullptr, (bf16*)nullptr, out, d_in[5], mode, 2);
}

// Round 21
// 169.519 us; speedup vs baseline: 1.2337x; 1.0044x over previous
//
#include <hip/hip_runtime.h>

#define BB 4
#define LL 2048
#define EE 1024
#define HH 8
#define DD 128
#define OO 1024
#define MM (BB*LL)   // 8192
#define ND (HH*DD)   // 1024

#define QBLK 128
#define KVBLK 64
#define NT (LL / KVBLK)

// log2(e)/sqrt(128): folded into qx at proj-q epilogue
#define C2 0.12751920678739807f

typedef __bf16 bf16;
typedef unsigned short u16;
typedef __bf16 bf16x8 __attribute__((ext_vector_type(8)));
typedef __bf16 bf16x4 __attribute__((ext_vector_type(4)));
typedef float  f32x4  __attribute__((ext_vector_type(4)));

// async global->LDS, 16B per lane; LDS dest = wave-uniform base + lane*16
__device__ __forceinline__ void gl16(const bf16* g, bf16* l) {
#if __has_builtin(__builtin_amdgcn_global_load_lds)
    __builtin_amdgcn_global_load_lds((const __attribute__((address_space(1))) char*)g,
                                     (__attribute__((address_space(3))) char*)l, 16, 0, 0);
#else
    *(bf16x8*)l = *(const bf16x8*)g;
#endif
}

// raw v_exp_f32 (args provably in (0,16.4]: no fixup needed)
__device__ __forceinline__ float fexp2(float x) {
#if __has_builtin(__builtin_amdgcn_exp2f)
    return __builtin_amdgcn_exp2f(x);
#else
    return exp2f(x);
#endif
}

__device__ __forceinline__ bf16x8 cvt8p(float4 f0, float4 f1) {
    bf16x8 v;
    v[0] = (bf16)f0.x; v[1] = (bf16)f0.y; v[2] = (bf16)f0.z; v[3] = (bf16)f0.w;
    v[4] = (bf16)f1.x; v[5] = (bf16)f1.y; v[6] = (bf16)f1.z; v[7] = (bf16)f1.w;
    return v;
}

// ---------------------------------------------------------------------------
// dtype detector (1 wave, parallel)
// ---------------------------------------------------------------------------
__global__ void detect_kernel(const u16* __restrict__ data, int* __restrict__ mode) {
    const int l = threadIdx.x;   // 64 threads
    int cnt = 0;
#pragma unroll
    for (int i = 0; i < 8; i++) {
        int e = (data[l * 8 + i] >> 7) & 0xFF;
        cnt += (e >= 117 && e <= 132) ? 1 : 0;
    }
    cnt += __shfl_xor(cnt, 1);
    cnt += __shfl_xor(cnt, 2);
    cnt += __shfl_xor(cnt, 4);
    cnt += __shfl_xor(cnt, 8);
    cnt += __shfl_xor(cnt, 16);
    cnt += __shfl_xor(cnt, 32);
    if (l == 0) *mode = (cnt > 400) ? 1 : 0;
}

__global__ __launch_bounds__(256) void fill_kernel(float* __restrict__ out, float v, int n) {
    int i = blockIdx.x * 256 + threadIdx.x;
    if (i < n) out[i] = v;
}

// ---------------------------------------------------------------------------
// w [H, E, D] (f32 or bf16)  ->  wT [H, D, E] bf16   (both weights, y=which)
// ---------------------------------------------------------------------------
__global__ __launch_bounds__(256) void wtrans_kernel(const void* __restrict__ in0,
                                                     const void* __restrict__ in1,
                                                     bf16* __restrict__ outT0,
                                                     bf16* __restrict__ outT1,
                                                     const int* __restrict__ mode) {
    const void* in = blockIdx.y ? in1 : in0;
    bf16* outT = blockIdx.y ? outT1 : outT0;
    int idx = blockIdx.x * 256 + threadIdx.x;   // over H*E*D/4
    int i4 = idx * 4;
    int h = i4 >> 17;            // E*D = 131072
    int rem = i4 & 131071;
    int e = rem >> 7;            // D = 128
    int d = rem & 127;
    size_t ob = ((size_t)h * DD + d) * EE + e;
    if (*mode) {
        bf16x4 v = *(const bf16x4*)((const bf16*)in + i4);
        outT[ob]          = v[0];
        outT[ob + EE]     = v[1];
        outT[ob + 2 * EE] = v[2];
        outT[ob + 3 * EE] = v[3];
    } else {
        float4 v = *(const float4*)((const float*)in + i4);
        outT[ob]          = (bf16)v.x;
        outT[ob + EE]     = (bf16)v.y;
        outT[ob + 2 * EE] = (bf16)v.z;
        outT[ob + 3 * EE] = (bf16)v.w;
    }
}

// ---------------------------------------------------------------------------
// Unified 8192x1024x1024 GEMM, C = A @ BT^T.  128x128 tile, BK=64, 4 waves.
// The f32 operand (A for epi3, B for epi2 when mode==0) is register-
// prefetched one K-tile ahead (loads issued after barrier-2 so they fly
// under the MFMAs); the bf16 operand always uses global_load_lds with
// inverse-swizzled source.
// epi==3: merged projections, 1024 blocks; half 0: sigmoid -> outBF0 + outT
//         (kxT layout), half 1: sigmoid*C2 -> outBF1 (qx pre-scaled).
// epi==2: out-proj, 512 blocks: +bias -> outF (f32).
// ---------------------------------------------------------------------------
__global__ __launch_bounds__(256) void gemm_kernel(const void* __restrict__ A0,
                                                   const void* __restrict__ A1,
                                                   const void* __restrict__ BT0,
                                                   const void* __restrict__ BT1,
                                                   bf16* __restrict__ outBF0,
                                                   bf16* __restrict__ outBF1,
                                                   bf16* __restrict__ outT,
                                                   float* __restrict__ outF,
                                                   const void* __restrict__ PB,
                                                   const int* __restrict__ mode,
                                                   const int epi) {
    __shared__ __align__(16) bf16 As[128 * 64];
    __shared__ __align__(16) bf16 Bs[128 * 64];
    const int md = *mode;
    const int t = threadIdx.x;
    const int w = t >> 6, l = t & 63;
    const int lr = l & 15, lg = l >> 4;
    const int wr = w >> 1, wc = w & 1;
    // XCD-grouped remap (bijective per 512-block half)
    const int o = blockIdx.x + (blockIdx.y << 3);
    const int half = (epi == 3) ? (o >> 9) : 0;
    const int oo = o & 511;
    const int mt = (oo & 7) * 8 + ((oo >> 3) & 7);
    const int ntile = oo >> 6;
    const int m0 = mt * 128, n0 = ntile * 128;
    const void* A = half ? A1 : A0;
    const void* BT = half ? BT1 : BT0;

    // f32-side (register-prefetched) vs bf16-side (global_load_lds) selection
    const int useF = (md == 0);
    const float* fS = (const float*)((epi == 3) ? A : BT);   // f32 operand
    bf16* fDst = (epi == 3) ? As : Bs;
    const int f0 = (epi == 3) ? m0 : n0;
    const bf16* gS = (const bf16*)((epi == 3) ? BT : A);     // the other operand
    bf16* gDst = (epi == 3) ? Bs : As;
    const int g0 = (epi == 3) ? n0 : m0;

    f32x4 acc[4][4];
    const f32x4 zero = {0.f, 0.f, 0.f, 0.f};
#pragma unroll
    for (int i = 0; i < 4; i++)
#pragma unroll
        for (int j = 0; j < 4; j++) acc[i][j] = zero;

    float4 rS[4][2];
    if (useF) {
#pragma unroll
        for (int p = 0; p < 4; p++) {
            const int id = p * 256 + t;
            const int row = id >> 3, cc = id & 7;
            const float* src = fS + (size_t)(f0 + row) * 1024 + cc * 8;
            rS[p][0] = *(const float4*)src;
            rS[p][1] = *(const float4*)(src + 4);
        }
    }

    for (int kt = 0; kt < 16; ++kt) {
        const int k0 = kt * 64;
        __syncthreads();
        if (useF) {
#pragma unroll
            for (int p = 0; p < 4; p++) {
                const int id = p * 256 + t;
                const int row = id >> 3, cc = id & 7;
                *(bf16x8*)(fDst + row * 64 + ((cc ^ (row & 7)) << 3)) = cvt8p(rS[p][0], rS[p][1]);
            }
#pragma unroll
            for (int p = 0; p < 4; p++) {
                const int id = p * 256 + t;
                const int row = id >> 3;
                const int c = (id & 7) ^ (row & 7);
                gl16(gS + (size_t)(g0 + row) * 1024 + k0 + c * 8, gDst + (p * 256 + w * 64) * 8);
            }
        } else {
#pragma unroll
            for (int p = 0; p < 4; p++) {
                const int id = p * 256 + t;
                const int row = id >> 3;
                const int c = (id & 7) ^ (row & 7);
                gl16((const bf16*)A + (size_t)(m0 + row) * 1024 + k0 + c * 8,
                     As + (p * 256 + w * 64) * 8);
                gl16((const bf16*)BT + (size_t)(n0 + row) * 1024 + k0 + c * 8,
                     Bs + (p * 256 + w * 64) * 8);
            }
        }
        __syncthreads();
        // issue next-tile f32 loads AFTER the barrier: they fly under the MFMAs
        if (useF && kt + 1 < 16) {
            const int k0n = k0 + 64;
#pragma unroll
            for (int p = 0; p < 4; p++) {
                const int id = p * 256 + t;
                const int row = id >> 3, cc = id & 7;
                const float* src = fS + (size_t)(f0 + row) * 1024 + k0n + cc * 8;
                rS[p][0] = *(const float4*)src;
                rS[p][1] = *(const float4*)(src + 4);
            }
        }
        bf16x8 af[4][2], bg[4][2];
#pragma unroll
        for (int i = 0; i < 4; i++) {
            const int ar = wr * 64 + i * 16 + lr;
#pragma unroll
            for (int ks = 0; ks < 2; ks++)
                af[i][ks] = *(const bf16x8*)(As + ar * 64 + (((ks * 4 + lg) ^ (ar & 7)) << 3));
        }
#pragma unroll
        for (int j = 0; j < 4; j++) {
            const int br = wc * 64 + j * 16 + lr;
#pragma unroll
            for (int ks = 0; ks < 2; ks++)
                bg[j][ks] = *(const bf16x8*)(Bs + br * 64 + (((ks * 4 + lg) ^ (br & 7)) << 3));
        }
#pragma unroll
        for (int i = 0; i < 4; i++)
#pragma unroll
            for (int j = 0; j < 4; j++) {
                acc[i][j] = __builtin_amdgcn_mfma_f32_16x16x32_bf16(af[i][0], bg[j][0], acc[i][j], 0, 0, 0);
                acc[i][j] = __builtin_amdgcn_mfma_f32_16x16x32_bf16(af[i][1], bg[j][1], acc[i][j], 0, 0, 0);
            }
    }

    if (epi == 3) {
        bf16* outBF = half ? outBF1 : outBF0;
        const float mulf = half ? C2 : 1.0f;
        const int b_idx = m0 >> 11;
        const int h = n0 >> 7;
#pragma unroll
        for (int i = 0; i < 4; i++) {
#pragma unroll
            for (int j = 0; j < 4; j++) {
                const int gr = m0 + wr * 64 + i * 16 + lg * 4;
                const int gc = n0 + wc * 64 + j * 16 + lr;
                float s0 = mulf / (1.0f + __expf(-acc[i][j][0]));
                float s1 = mulf / (1.0f + __expf(-acc[i][j][1]));
                float s2 = mulf / (1.0f + __expf(-acc[i][j][2]));
                float s3 = mulf / (1.0f + __expf(-acc[i][j][3]));
                outBF[(size_t)gr * ND + gc]           = (bf16)s0;
                outBF[(size_t)(gr + 1) * ND + gc]     = (bf16)s1;
                outBF[(size_t)(gr + 2) * ND + gc]     = (bf16)s2;
                outBF[(size_t)(gr + 3) * ND + gc]     = (bf16)s3;
                if (!half) {
                    bf16x4 pk;
                    pk[0] = (bf16)s0; pk[1] = (bf16)s1; pk[2] = (bf16)s2; pk[3] = (bf16)s3;
                    const int d = gc & 127;
                    const int lrow = gr & 2047;
                    *(bf16x4*)(outT + (((size_t)(h * BB + b_idx)) * DD + d) * LL + lrow) = pk;
                }
            }
        }
    } else {
#pragma unroll
        for (int j = 0; j < 4; j++) {
            const int gc = n0 + wc * 64 + j * 16 + lr;
            const float bias = md ? (float)((const bf16*)PB)[gc] : ((const float*)PB)[gc];
#pragma unroll
            for (int i = 0; i < 4; i++) {
                const int gr = m0 + wr * 64 + i * 16 + lg * 4;
#pragma unroll
                for (int reg = 0; reg < 4; reg++)
                    outF[(size_t)(gr + reg) * OO + gc] = acc[i][j][reg] + bias;
            }
        }
    }
}

// ---------------------------------------------------------------------------
// attention (round-17/20 structure + ones-MFMA row-sum): async gl_lds staging
// with pre-swizzled global source + linear LDS dest; K/V double-buffered,
// 1 barrier/tile; swapped QK^T = mfma(K,Q); PV = mfma(V^T,P) -> O^T.
// Softmax denominator now computed by appending osum = mfma(ones, P):
// every output reg = sum_kv P[kv][q], accumulated across tiles — replaces
// 16 VALU adds/tile + epilogue shuffles with 2 MFMAs/tile on the
// under-utilized MFMA pipe.
// ---------------------------------------------------------------------------
__global__ __launch_bounds__(512, 4) void attn_kernel(const bf16* __restrict__ QX,
                                                      const bf16* __restrict__ KX,
                                                      const bf16* __restrict__ KXT,
                                                      bf16* __restrict__ AO) {
    __shared__ __align__(16) bf16 Kl[2][KVBLK * 128];   // 32 KiB
    __shared__ __align__(16) bf16 Vt[2][128 * KVBLK];   // 32 KiB
    __shared__ __align__(16) bf16 Pl[8][16 * 64];       // 16 KiB
    const int t = threadIdx.x;
    const int w = t >> 6, l = t & 63;
    const int lr = l & 15, lg = l >> 4;
    // XCD-chunked remap: dispatched bid -> orig linear id (bh-major)
    const int bid = blockIdx.x;
    const int orig = (bid & 7) * 64 + (bid >> 3);
    const int bh = orig >> 4;
    const int h = bh & 7, b = bh >> 3;
    const int q0 = (orig & 15) * QBLK;
    const bf16* qxh = QX + (size_t)(b * LL) * ND + h * DD;
    const bf16* kxh = KX + (size_t)(b * LL) * ND + h * DD;
    const bf16* kxt = KXT + ((size_t)(h * BB + b)) * DD * LL;

    // staging: 2 K-chunks + 2 V-chunks per thread, LINEAR LDS dest id*16B,
    // global source chunk pre-swizzled (src = destchunk ^ (row & mask))
    const int kid1 = 512 + t;
    const int krow0 = t >> 4,    kcd0 = t & 15;
    const int krow1 = kid1 >> 4, kcd1 = kid1 & 15;
    const int vrow0 = t >> 3,    vcd0 = t & 7;
    const int vrow1 = kid1 >> 3, vcd1 = kid1 & 7;
    const bf16* kps0 = kxh + (size_t)krow0 * ND + (kcd0 ^ (krow0 & 15)) * 8;
    const bf16* kps1 = kxh + (size_t)krow1 * ND + (kcd1 ^ (krow1 & 15)) * 8;
    const bf16* vps0 = kxt + (size_t)vrow0 * LL + (vcd0 ^ (vrow0 & 7)) * 8;
    const bf16* vps1 = kxt + (size_t)vrow1 * LL + (vcd1 ^ (vrow1 & 7)) * 8;

    // Q fragments (q row = lane&15), register resident; QX pre-scaled by C2
    bf16x8 qf[4];
    const int qrow = q0 + w * 16 + lr;
#pragma unroll
    for (int s = 0; s < 4; s++)
        qf[s] = *(const bf16x8*)(qxh + (size_t)qrow * ND + s * 32 + lg * 8);

    // ones fragment for the row-sum MFMA
    bf16x8 ones8;
#pragma unroll
    for (int i = 0; i < 8; i++) ones8[i] = (bf16)1.0f;

    // prologue: async-stage tile 0 -> buf0; barrier drains vmcnt
    gl16(kps0, Kl[0] + t * 8);
    gl16(kps1, Kl[0] + kid1 * 8);
    gl16(vps0, Vt[0] + t * 8);
    gl16(vps1, Vt[0] + kid1 * 8);
    __syncthreads();

    f32x4 oacc[8];   // O^T: oacc[n][reg] = O[d = n*16+lg*4+reg][q = lr]
    const f32x4 zero = {0.f, 0.f, 0.f, 0.f};
#pragma unroll
    for (int n = 0; n < 8; n++) oacc[n] = zero;
    f32x4 osum = zero;   // every reg = running sum_kv P[kv][q=lr]

    for (int kt = 0; kt < NT; ++kt) {
        const int cur = kt & 1;
        if (kt + 1 < NT) {
            const size_t ko = (size_t)(kt + 1) * KVBLK * ND;
            const int vo = (kt + 1) * KVBLK;
            gl16(kps0 + ko, Kl[cur ^ 1] + t * 8);
            gl16(kps1 + ko, Kl[cur ^ 1] + kid1 * 8);
            gl16(vps0 + vo, Vt[cur ^ 1] + t * 8);
            gl16(vps1 + vo, Vt[cur ^ 1] + kid1 * 8);
        }
        const bf16* KlC = Kl[cur];
        const bf16* VtC = Vt[cur];

        // ---- kv half A (n = 0,1; kv 0..31) ----
        f32x4 sa[4];
        __builtin_amdgcn_s_setprio(1);
#pragma unroll
        for (int n = 0; n < 2; n++) {
            sa[n] = zero;
#pragma unroll
            for (int ks = 0; ks < 4; ks++) {
                int arow = n * 16 + lr;   // kv row
                bf16x8 kb = *(const bf16x8*)(KlC + arow * 128 + ((((ks * 4 + lg) ^ (arow & 15))) << 3));
                sa[n] = __builtin_amdgcn_mfma_f32_16x16x32_bf16(kb, qf[ks], sa[n], 0, 0, 0);
            }
        }
        __builtin_amdgcn_s_setprio(0);
#pragma unroll
        for (int n = 0; n < 2; n++) {
            bf16x4 pk;
#pragma unroll
            for (int j = 0; j < 4; j++) pk[j] = (bf16)fexp2(sa[n][j]);
            const int chunk = (2 * n + (lg >> 1)) ^ (lr & 7);
            *(bf16x4*)(Pl[w] + lr * 64 + chunk * 8 + (lg & 1) * 4) = pk;
        }
        // ---- kv half B (n = 2,3; kv 32..63) — its MFMAs overlap half-A VALU ----
        __builtin_amdgcn_s_setprio(1);
#pragma unroll
        for (int n = 2; n < 4; n++) {
            sa[n] = zero;
#pragma unroll
            for (int ks = 0; ks < 4; ks++) {
                int arow = n * 16 + lr;
                bf16x8 kb = *(const bf16x8*)(KlC + arow * 128 + ((((ks * 4 + lg) ^ (arow & 15))) << 3));
                sa[n] = __builtin_amdgcn_mfma_f32_16x16x32_bf16(kb, qf[ks], sa[n], 0, 0, 0);
            }
        }
        __builtin_amdgcn_s_setprio(0);
#pragma unroll
        for (int n = 2; n < 4; n++) {
            bf16x4 pk;
#pragma unroll
            for (int j = 0; j < 4; j++) pk[j] = (bf16)fexp2(sa[n][j]);
            const int chunk = (2 * n + (lg >> 1)) ^ (lr & 7);
            *(bf16x4*)(Pl[w] + lr * 64 + chunk * 8 + (lg & 1) * 4) = pk;
        }
        // wave-local ordering: P stores above vs vector-loads below
        asm volatile("s_waitcnt lgkmcnt(0)" ::: "memory");
        __builtin_amdgcn_sched_barrier(0);
        // PV: O^T += V^T P  (A = V^T rows d, B = P rows q)
        bf16x8 pb0 = *(const bf16x8*)(Pl[w] + lr * 64 + (((lg ^ (lr & 7))) << 3));
        bf16x8 pb1 = *(const bf16x8*)(Pl[w] + lr * 64 + ((((4 + lg) ^ (lr & 7))) << 3));
        __builtin_amdgcn_s_setprio(1);
#pragma unroll
        for (int n = 0; n < 8; n++) {
            int vrow = n * 16 + lr;
            bf16x8 vb0 = *(const bf16x8*)(VtC + vrow * 64 + (((lg ^ (vrow & 7))) << 3));
            oacc[n] = __builtin_amdgcn_mfma_f32_16x16x32_bf16(vb0, pb0, oacc[n], 0, 0, 0);
            bf16x8 vb1 = *(const bf16x8*)(VtC + vrow * 64 + ((((4 + lg) ^ (vrow & 7))) << 3));
            oacc[n] = __builtin_amdgcn_mfma_f32_16x16x32_bf16(vb1, pb1, oacc[n], 0, 0, 0);
        }
        // row-sum: every reg of osum += sum_kv P[kv][q=lr]
        osum = __builtin_amdgcn_mfma_f32_16x16x32_bf16(ones8, pb0, osum, 0, 0, 0);
        osum = __builtin_amdgcn_mfma_f32_16x16x32_bf16(ones8, pb1, osum, 0, 0, 0);
        __builtin_amdgcn_s_setprio(0);
        __syncthreads();
    }
    // epilogue: osum[0] already holds the full denominator for q = lr
    const float linv = 1.0f / osum[0];
    const int arow = b * LL + q0 + w * 16 + lr;   // one output row per lane
    bf16* aoRow = AO + (size_t)arow * ND + h * DD;
#pragma unroll
    for (int n = 0; n < 8; n++) {
        bf16x4 o;
#pragma unroll
        for (int reg = 0; reg < 4; reg++) o[reg] = (bf16)(oacc[n][reg] * linv);
        *(bf16x4*)(aoRow + n * 16 + lg * 4) = o;
    }
}

extern "C" void kernel_launch(void* const* d_in, const int* in_sizes, int n_in,
                              void* d_out, int out_size, void* d_ws, size_t ws_size,
                              hipStream_t stream) {
    (void)in_sizes; (void)n_in;
    float* out = (float*)d_out;

    const size_t NEED = ((size_t)(2 + 2 + 16 + 16 + 16 + 16) << 20) + 256;
    if (ws_size < NEED) {
        hipLaunchKernelGGL(fill_kernel, dim3((out_size + 255) / 256), dim3(256), 0, stream,
                           out, (float)(ws_size >> 20), out_size);
        return;
    }

    int* mode = (int*)d_ws;
    bf16* base = (bf16*)((char*)d_ws + 256);
    bf16* wkT = base;                              // [H, D, E]   2 MiB
    bf16* wqT = wkT + (size_t)HH * DD * EE;        // [H, D, E]   2 MiB
    bf16* kx  = wqT + (size_t)HH * DD * EE;        // [M, ND]    16 MiB
    bf16* qx  = kx  + (size_t)MM * ND;             // [M, ND]    16 MiB
    bf16* kxT = qx  + (size_t)MM * ND;             // [H, B, D, L] 16 MiB
    bf16* ao  = kxT + (size_t)HH * MM * DD;        // [M, ND]    16 MiB

    hipLaunchKernelGGL(detect_kernel, dim3(1), dim3(64), 0, stream, (const u16*)d_in[0], mode);
    hipLaunchKernelGGL(wtrans_kernel, dim3(HH * EE * DD / 4 / 256, 2), dim3(256), 0, stream,
                       d_in[2], d_in[3], wkT, wqT, mode);
    // merged proj-k (sigmoid + kxT) and proj-q (sigmoid*C2): 1024 blocks
    hipLaunchKernelGGL(gemm_kernel, dim3(8, 128), dim3(256), 0, stream,
                       d_in[0], d_in[1], wkT, wqT, kx, qx, kxT,
                       (float*)nullptr, (const void*)nullptr, mode, 3);
    // attention
    hipLaunchKernelGGL(attn_kernel, dim3(512), dim3(512), 0, stream, qx, kx, kxT, ao);
    // out-proj (+bias, f32 out); B = proj_w (f32 reg-staged or bf16 gload)
    hipLaunchKernelGGL(gemm_kernel, dim3(8, 64), dim3(256), 0, stream,
                       ao, (const void*)nullptr, d_in[4], (const void*)nullptr,
                       (bf16*)nullptr, (bf16*)nullptr, (bf16*)nullptr, out, d_in[5], mode, 2);
}